// Round 6
// baseline (230.050 us; speedup 1.0000x reference)
//
#include <hip/hip_runtime.h>

#define NN 512

typedef __attribute__((ext_vector_type(8))) short bf16x8;
typedef __attribute__((ext_vector_type(4))) float f32x4;

__device__ __forceinline__ unsigned short f2bf(float x) {
    union { float f; unsigned u; } c; c.f = x;
    unsigned u = c.u + 0x7fffu + ((c.u >> 16) & 1u);
    return (unsigned short)(u >> 16);
}

__device__ __forceinline__ int find_bin(float d) {
    int bin = 22;  // 22 = "no bin" (zero row in WdT/WscT)
    #pragma unroll
    for (int k = 0; k < 22; ++k) {
        float lo = (float)(1e-3 + k * ((20.0 - 1e-3) / 21.0));
        float hi = (k < 21) ? (float)(1e-3 + (k + 1) * ((20.0 - 1e-3) / 21.0)) : 1e8f;
        if (d > lo && d < hi) bin = k;
    }
    return bin;
}

// ---- fused prep: W1-column gathers, W2/W3 MFMA-fragment packs, relpos table,
//      p_i node embed, and the per-pair distogram bin table ----
__global__ __launch_bounds__(128) void k_prep(
        const float* __restrict__ s, const float* __restrict__ t,
        const float* __restrict__ sct,
        const float* __restrict__ Wsp, const float* __restrict__ bsp,
        const float* __restrict__ Wrp, const float* __restrict__ brp,
        const float* __restrict__ W1, const float* __restrict__ b1,
        const float* __restrict__ W2, const float* __restrict__ W3,
        float* __restrict__ p_i, float* __restrict__ relT,
        float* __restrict__ WdT, float* __restrict__ WscT,
        unsigned short* __restrict__ w2a, unsigned short* __restrict__ w3a,
        unsigned short* __restrict__ binT)
{
    __shared__ float sh[2][256];
    const int blk = blockIdx.x, tid = threadIdx.x;

    if (blk < 23) {
        // W1 distogram column gathers (row 22 = zeros)
        const int bin = blk, c = tid;
        WdT[bin * 128 + c]  = (bin < 22) ? W1[c * 236 + 192 + bin] : 0.0f;
        WscT[bin * 128 + c] = (bin < 22) ? W1[c * 236 + 214 + bin] : 0.0f;
    } else if (blk < 55) {
        // pack W2/W3 (128x128) into MFMA A-fragment order, bf16.
        // entry idx holds W[ct*16 + (lane&15)][ks*32 + (lane>>4)*8 + e]
        const int seg = blk - 23;           // 0..31
        const int isW3 = seg >> 4;
        const int idx = (seg & 15) * 128 + tid;   // 0..2047
        const int lane = idx & 63, ks = (idx >> 6) & 3, ct = idx >> 8;
        const float* W = isW3 ? W3 : W2;
        unsigned short* dst = isW3 ? w3a : w2a;
        const float* wp = W + (ct * 16 + (lane & 15)) * 128 + ks * 32 + (lane >> 4) * 8;
        unsigned r0 = (unsigned)f2bf(wp[0]) | ((unsigned)f2bf(wp[1]) << 16);
        unsigned r1 = (unsigned)f2bf(wp[2]) | ((unsigned)f2bf(wp[3]) << 16);
        unsigned r2 = (unsigned)f2bf(wp[4]) | ((unsigned)f2bf(wp[5]) << 16);
        unsigned r3 = (unsigned)f2bf(wp[6]) | ((unsigned)f2bf(wp[7]) << 16);
        uint4 v = { r0, r1, r2, r3 };
        *(uint4*)(dst + idx * 8) = v;
    } else if (blk < 1078) {
        // relT[d] = (pos_emb(d) @ W_rp^T + b_rp) @ W1[:,128:192]^T + b1
        const int row = blk - 55;           // 0..1022
        const float d = (float)(row - 511);
        if (tid < 32) {
            float f = powf(2056.0f, (float)tid * (1.0f / 32.0f));
            float ang = d * 3.14159265358979323846f / f;
            sh[0][tid] = sinf(ang);
            sh[0][tid + 32] = cosf(ang);
        }
        __syncthreads();
        if (tid < 64) {
            const float* wr = Wrp + tid * 64;
            float a = brp[tid];
            #pragma unroll
            for (int k = 0; k < 64; ++k) a += sh[0][k] * wr[k];
            sh[1][tid] = a;
        }
        __syncthreads();
        const float* w = W1 + tid * 236 + 128;
        float a = b1[tid];
        #pragma unroll
        for (int k = 0; k < 64; ++k) a += sh[1][k] * w[k];
        relT[row * 128 + tid] = a;
    } else if (blk < 1590) {
        // p_i = s @ Wsp^T + bsp, two rows per block
        const int half = tid >> 6, ch = tid & 63;
        const int row = (blk - 1078) * 2 + half;
        *(float4*)&sh[half][ch * 4] = *(const float4*)&s[row * 256 + ch * 4];
        __syncthreads();
        const float* w = Wsp + ch * 256;
        float acc = bsp[ch];
        #pragma unroll 8
        for (int k = 0; k < 256; k += 4)
            acc += sh[half][k]*w[k] + sh[half][k+1]*w[k+1] + sh[half][k+2]*w[k+2] + sh[half][k+3]*w[k+3];
        p_i[row * 64 + ch] = acc;
    } else {
        // distogram bins for every (bi, j) pair, packed
        const int pair = (blk - 1590) * 128 + tid;   // 0..524287
        const int bi = pair >> 9, j = pair & (NN - 1);
        const int rj = (bi & ~(NN - 1)) + j;
        float ax = t[bi*3+0] - t[rj*3+0];
        float ay = t[bi*3+1] - t[rj*3+1];
        float az = t[bi*3+2] - t[rj*3+2];
        int bD = find_bin(sqrtf(ax*ax + ay*ay + az*az));
        float sx = sct[bi*3+0] - sct[rj*3+0];
        float sy = sct[bi*3+1] - sct[rj*3+1];
        float sz = sct[bi*3+2] - sct[rj*3+2];
        int bS = find_bin(sqrtf(sx*sx + sy*sy + sz*sz));
        binT[pair] = (unsigned short)(bD | (bS << 5));
    }
}

// ---- qL/qR: per-node contributions through W1 cols [0:64) and [64:128) ----
__global__ __launch_bounds__(128) void k_ql(const float* __restrict__ p_i,
        const float* __restrict__ W1, float* __restrict__ qL, float* __restrict__ qR)
{
    __shared__ float pr[64];
    const int row = blockIdx.x, tid = threadIdx.x;
    if (tid < 16) *(float4*)&pr[tid * 4] = *(const float4*)&p_i[row * 64 + tid * 4];
    __syncthreads();
    const float* w = W1 + tid * 236;
    float aL = 0.f, aR = 0.f;
    #pragma unroll
    for (int k = 0; k < 64; ++k) { aL += pr[k] * w[k]; aR += pr[k] * w[64 + k]; }
    qL[row * 128 + tid] = aL;
    qR[row * 128 + tid] = aR;
}

// ---- main fused kernel: two-phase 32KB weight staging (W2 then W3 over the
//      same buffer); 2 tiles per wave; h2 D-frag -> B-frag via the verified
//      per-wave LDS round-trip (R3 path); direct D-frag stores. ----
__global__ __launch_bounds__(256, 3) void k_main(
    const float* __restrict__ pmask,
    const float* __restrict__ qL, const float* __restrict__ qR,
    const float* __restrict__ relT, const float* __restrict__ WdT,
    const float* __restrict__ WscT, const unsigned short* __restrict__ binT,
    const unsigned short* __restrict__ w2a, const unsigned short* __restrict__ w3a,
    const float* __restrict__ b2, const float* __restrict__ b3,
    const float* __restrict__ lng, const float* __restrict__ lnb,
    float* __restrict__ out)
{
    __shared__ char wsh[32768];       // one full fragment table (W2, then W3)
    __shared__ char h2buf[4][4096];   // per-wave h2 tile, XOR-swizzled (R3 path)

    const int tid  = threadIdx.x;
    const int l    = tid & 63;
    const int w    = tid >> 6;
    const int jloc = l & 15;
    const int gq   = l >> 4;

    const int blk   = blockIdx.x;
    const int bi    = blk >> 2;               // b*512 + i
    const int i     = bi & (NN - 1);
    const int bbase = bi & ~(NN - 1);
    const int j0    = (blk & 3) * 128;        // block covers j0..j0+127

    // ---- phase 0: stage W2 fragment table (full 32KB) ----
    {
        const float4* g2 = (const float4*)w2a;   // 2048 float4
        float4* lw = (float4*)wsh;
        #pragma unroll
        for (int r = 0; r < 8; ++r) lw[r * 256 + tid] = g2[r * 256 + tid];
    }
    __syncthreads();

    bf16x8 b3f[2][4];
    float  maskv[2];
    char* hb = h2buf[w];
    const int rswz = (jloc & 7) << 4;

    // ---- phase 1: per tile, build h1 frags, GEMM2 (W2 from LDS),
    //      h2 -> per-wave LDS -> B-frags ----
    #pragma unroll
    for (int tt = 0; tt < 2; ++tt) {
        const int j = j0 + tt * 64 + w * 16 + jloc;

        const unsigned bv = binT[bi * NN + j];
        const int binD = bv & 31, binSC = (int)(bv >> 5);
        maskv[tt] = pmask[(size_t)bi * NN + j];

        const float* qLp = qL + bi * 128;
        const float* qRp = qR + (bbase + j) * 128;
        const float* rTp = relT + (i - j + NN - 1) * 128;
        const float* dTp = WdT + binD * 128;
        const float* sTp = WscT + binSC * 128;

        // h1 = relu(qL + qR + relT + WdT[bin] + WscT[bin]) as B-fragments
        bf16x8 bfr[4];
        #pragma unroll
        for (int ks = 0; ks < 4; ++ks) {
            const int c0 = ks * 32 + gq * 8;
            float x[8];
            #pragma unroll
            for (int h = 0; h < 2; ++h) {
                const int c = c0 + h * 4;
                float4 v0 = *(const float4*)(qLp + c);
                float4 v1 = *(const float4*)(qRp + c);
                float4 v2 = *(const float4*)(rTp + c);
                float4 v3 = *(const float4*)(dTp + c);
                float4 v4 = *(const float4*)(sTp + c);
                x[h*4+0] = fmaxf(v0.x + v1.x + v2.x + v3.x + v4.x, 0.0f);
                x[h*4+1] = fmaxf(v0.y + v1.y + v2.y + v3.y + v4.y, 0.0f);
                x[h*4+2] = fmaxf(v0.z + v1.z + v2.z + v3.z + v4.z, 0.0f);
                x[h*4+3] = fmaxf(v0.w + v1.w + v2.w + v3.w + v4.w, 0.0f);
            }
            bf16x8 r;
            #pragma unroll
            for (int e = 0; e < 8; ++e) r[e] = (short)f2bf(x[e]);
            bfr[ks] = r;
        }

        // GEMM2: A = W2 frags (LDS), B = h1
        f32x4 acc2[8];
        #pragma unroll
        for (int ct = 0; ct < 8; ++ct) {
            f32x4 c4 = {0.f, 0.f, 0.f, 0.f};
            #pragma unroll
            for (int ks = 0; ks < 4; ++ks) {
                bf16x8 af = *(bf16x8*)(wsh + (ct * 256 + ks * 64 + l) * 16);
                c4 = __builtin_amdgcn_mfma_f32_16x16x32_bf16(af, bfr[ks], c4, 0, 0, 0);
            }
            acc2[ct] = c4;
        }

        // h2 = relu(acc2 + b2) -> per-wave LDS (each lane owns 4 consecutive
        // channels of row jloc) -> ds_write_b64  [verified R3 path]
        #pragma unroll
        for (int ct = 0; ct < 8; ++ct) {
            const int c = ct * 16 + gq * 4;
            float4 bb = *(const float4*)(b2 + c);
            float y0 = fmaxf(acc2[ct][0] + bb.x, 0.0f);
            float y1 = fmaxf(acc2[ct][1] + bb.y, 0.0f);
            float y2 = fmaxf(acc2[ct][2] + bb.z, 0.0f);
            float y3 = fmaxf(acc2[ct][3] + bb.w, 0.0f);
            uint2 pk;
            pk.x = (unsigned)f2bf(y0) | ((unsigned)f2bf(y1) << 16);
            pk.y = (unsigned)f2bf(y2) | ((unsigned)f2bf(y3) << 16);
            *(uint2*)(hb + ((jloc * 256 + c * 2) ^ rswz)) = pk;
        }

        // read back as GEMM3 B-fragments (wave-local, in-order DS pipe)
        #pragma unroll
        for (int ks = 0; ks < 4; ++ks)
            b3f[tt][ks] = *(bf16x8*)(hb + ((jloc * 256 + ks * 64 + gq * 16) ^ rswz));
    }

    // ---- phase 2: swap weight buffer to W3 ----
    __syncthreads();   // everyone done reading W2 (b3f regs already loaded)
    {
        const float4* g3 = (const float4*)w3a;
        float4* lw = (float4*)wsh;
        #pragma unroll
        for (int r = 0; r < 8; ++r) lw[r * 256 + tid] = g3[r * 256 + tid];
    }
    __syncthreads();

    // ---- phase 3: per tile, GEMM3 (W3 from LDS), LN, scale, mask, store ----
    #pragma unroll
    for (int tt = 0; tt < 2; ++tt) {
        f32x4 acc3[8];
        #pragma unroll
        for (int ct = 0; ct < 8; ++ct) {
            f32x4 c4 = {0.f, 0.f, 0.f, 0.f};
            #pragma unroll
            for (int ks = 0; ks < 4; ++ks) {
                bf16x8 af = *(bf16x8*)(wsh + (ct * 256 + ks * 64 + l) * 16);
                c4 = __builtin_amdgcn_mfma_f32_16x16x32_bf16(af, b3f[tt][ks], c4, 0, 0, 0);
            }
            acc3[ct] = c4;
        }

        float s1 = 0.f, s2 = 0.f;
        #pragma unroll
        for (int ct = 0; ct < 8; ++ct) {
            const int c = ct * 16 + gq * 4;
            float4 bb = *(const float4*)(b3 + c);
            acc3[ct][0] += bb.x; acc3[ct][1] += bb.y;
            acc3[ct][2] += bb.z; acc3[ct][3] += bb.w;
            #pragma unroll
            for (int r = 0; r < 4; ++r) { float v = acc3[ct][r]; s1 += v; s2 += v * v; }
        }
        s1 += __shfl_xor(s1, 16); s2 += __shfl_xor(s2, 16);
        s1 += __shfl_xor(s1, 32); s2 += __shfl_xor(s2, 32);
        const float mean = s1 * (1.0f / 128.0f);
        const float var  = s2 * (1.0f / 128.0f) - mean * mean;
        const float rstd = rsqrtf(var + 1e-5f);
        const float mk = maskv[tt];

        float* op = out + ((size_t)(bi * NN + j0 + tt * 64 + w * 16 + jloc)) * 128;
        #pragma unroll
        for (int ct = 0; ct < 8; ++ct) {
            const int c = ct * 16 + gq * 4;
            float4 g4 = *(const float4*)(lng + c);
            float4 be = *(const float4*)(lnb + c);
            float4 o;
            o.x = ((acc3[ct][0] - mean) * rstd * g4.x + be.x) * mk;
            o.y = ((acc3[ct][1] - mean) * rstd * g4.y + be.y) * mk;
            o.z = ((acc3[ct][2] - mean) * rstd * g4.z + be.z) * mk;
            o.w = ((acc3[ct][3] - mean) * rstd * g4.w + be.w) * mk;
            *(float4*)(op + c) = o;
        }
    }
}

extern "C" void kernel_launch(void* const* d_in, const int* in_sizes, int n_in,
                              void* d_out, int out_size, void* d_ws, size_t ws_size,
                              hipStream_t stream)
{
    const float* s   = (const float*)d_in[0];
    const float* t   = (const float*)d_in[1];
    const float* sct = (const float*)d_in[2];
    const float* pm  = (const float*)d_in[3];
    const float* Wsp = (const float*)d_in[4];
    const float* bsp = (const float*)d_in[5];
    const float* Wrp = (const float*)d_in[6];
    const float* brp = (const float*)d_in[7];
    const float* W1  = (const float*)d_in[8];
    const float* b1  = (const float*)d_in[9];
    const float* W2  = (const float*)d_in[10];
    const float* b2  = (const float*)d_in[11];
    const float* W3  = (const float*)d_in[12];
    const float* b3  = (const float*)d_in[13];
    const float* lng = (const float*)d_in[14];
    const float* lnb = (const float*)d_in[15];

    float* ws   = (float*)d_ws;
    float* p_i  = ws;                                    // 65536
    float* qL   = ws + 65536;                            // 131072
    float* qR   = ws + 196608;                           // 131072
    float* relT = ws + 327680;                           // 130944
    float* WdT  = ws + 458624;                           // 2944
    float* WscT = ws + 461568;                           // 2944
    unsigned short* w2a  = (unsigned short*)(ws + 464512);   // 16384 u16 = 32KB
    unsigned short* w3a  = (unsigned short*)(ws + 472704);   // 16384 u16 = 32KB
    unsigned short* binT = (unsigned short*)(ws + 480896);   // 524288 u16

    k_prep<<<5686, 128, 0, stream>>>(s, t, sct, Wsp, bsp, Wrp, brp, W1, b1, W2, W3,
                                     p_i, relT, WdT, WscT, w2a, w3a, binT);
    k_ql<<<1024, 128, 0, stream>>>(p_i, W1, qL, qR);
    k_main<<<4096, 256, 0, stream>>>(pm, qL, qR, relT, WdT, WscT, binT,
                                     w2a, w3a, b2, b3, lng, lnb, (float*)d_out);
}

// Round 7
// 147.509 us; speedup vs baseline: 1.5596x; 1.5596x over previous
//
#include <hip/hip_runtime.h>

#define NN 512

typedef __attribute__((ext_vector_type(8))) short bf16x8;
typedef __attribute__((ext_vector_type(4))) float f32x4;

__device__ __forceinline__ unsigned short f2bf(float x) {
    union { float f; unsigned u; } c; c.f = x;
    unsigned u = c.u + 0x7fffu + ((c.u >> 16) & 1u);
    return (unsigned short)(u >> 16);
}

__device__ __forceinline__ float blo(unsigned u) {
    union { unsigned x; float f; } c; c.x = u << 16; return c.f;
}
__device__ __forceinline__ float bhi(unsigned u) {
    union { unsigned x; float f; } c; c.x = u & 0xffff0000u; return c.f;
}

// sum 5 packed bf16-pairs in fp32, relu, repack
__device__ __forceinline__ unsigned pk2(unsigned a, unsigned b, unsigned c,
                                        unsigned d, unsigned e) {
    float lo = blo(a) + blo(b) + blo(c) + blo(d) + blo(e);
    float hi = bhi(a) + bhi(b) + bhi(c) + bhi(d) + bhi(e);
    lo = fmaxf(lo, 0.0f);
    hi = fmaxf(hi, 0.0f);
    return (unsigned)f2bf(lo) | ((unsigned)f2bf(hi) << 16);
}

__device__ __forceinline__ int find_bin(float d) {
    int bin = 22;  // 22 = "no bin" (zero row in WdTb/WscTb)
    #pragma unroll
    for (int k = 0; k < 22; ++k) {
        float lo = (float)(1e-3 + k * ((20.0 - 1e-3) / 21.0));
        float hi = (k < 21) ? (float)(1e-3 + (k + 1) * ((20.0 - 1e-3) / 21.0)) : 1e8f;
        if (d > lo && d < hi) bin = k;
    }
    return bin;
}

// ---- fused prep: bf16 W1-column gathers, W2/W3 MFMA-fragment packs,
//      bf16 relpos table, p_i node embed, per-pair distogram bin table ----
__global__ __launch_bounds__(128) void k_prep(
        const float* __restrict__ s, const float* __restrict__ t,
        const float* __restrict__ sct,
        const float* __restrict__ Wsp, const float* __restrict__ bsp,
        const float* __restrict__ Wrp, const float* __restrict__ brp,
        const float* __restrict__ W1, const float* __restrict__ b1,
        const float* __restrict__ W2, const float* __restrict__ W3,
        float* __restrict__ p_i, unsigned short* __restrict__ relTb,
        unsigned short* __restrict__ WdTb, unsigned short* __restrict__ WscTb,
        unsigned short* __restrict__ w2a, unsigned short* __restrict__ w3a,
        unsigned short* __restrict__ binT)
{
    __shared__ float sh[2][256];
    const int blk = blockIdx.x, tid = threadIdx.x;

    if (blk < 23) {
        const int bin = blk, c = tid;
        WdTb[bin * 128 + c]  = (bin < 22) ? f2bf(W1[c * 236 + 192 + bin]) : (unsigned short)0;
        WscTb[bin * 128 + c] = (bin < 22) ? f2bf(W1[c * 236 + 214 + bin]) : (unsigned short)0;
    } else if (blk < 55) {
        // pack W2/W3 into A-fragment order: entry idx = ct*256 + ks*64 + lane
        // holds W[ct*16 + (lane&15)][ks*32 + (lane>>4)*8 + e]
        const int seg = blk - 23;
        const int isW3 = seg >> 4;
        const int idx = (seg & 15) * 128 + tid;
        const int lane = idx & 63, ks = (idx >> 6) & 3, ct = idx >> 8;
        const float* W = isW3 ? W3 : W2;
        unsigned short* dst = isW3 ? w3a : w2a;
        const float* wp = W + (ct * 16 + (lane & 15)) * 128 + ks * 32 + (lane >> 4) * 8;
        unsigned r0 = (unsigned)f2bf(wp[0]) | ((unsigned)f2bf(wp[1]) << 16);
        unsigned r1 = (unsigned)f2bf(wp[2]) | ((unsigned)f2bf(wp[3]) << 16);
        unsigned r2 = (unsigned)f2bf(wp[4]) | ((unsigned)f2bf(wp[5]) << 16);
        unsigned r3 = (unsigned)f2bf(wp[6]) | ((unsigned)f2bf(wp[7]) << 16);
        uint4 v = { r0, r1, r2, r3 };
        *(uint4*)(dst + idx * 8) = v;
    } else if (blk < 1078) {
        // relTb[d] = bf16( (pos_emb(d) @ W_rp^T + b_rp) @ W1[:,128:192]^T + b1 )
        const int row = blk - 55;
        const float d = (float)(row - 511);
        if (tid < 32) {
            float f = powf(2056.0f, (float)tid * (1.0f / 32.0f));
            float ang = d * 3.14159265358979323846f / f;
            sh[0][tid] = sinf(ang);
            sh[0][tid + 32] = cosf(ang);
        }
        __syncthreads();
        if (tid < 64) {
            const float* wr = Wrp + tid * 64;
            float a = brp[tid];
            #pragma unroll
            for (int k = 0; k < 64; ++k) a += sh[0][k] * wr[k];
            sh[1][tid] = a;
        }
        __syncthreads();
        const float* w = W1 + tid * 236 + 128;
        float a = b1[tid];
        #pragma unroll
        for (int k = 0; k < 64; ++k) a += sh[1][k] * w[k];
        relTb[row * 128 + tid] = f2bf(a);
    } else if (blk < 1590) {
        // p_i = s @ Wsp^T + bsp, two rows per block
        const int half = tid >> 6, ch = tid & 63;
        const int row = (blk - 1078) * 2 + half;
        *(float4*)&sh[half][ch * 4] = *(const float4*)&s[row * 256 + ch * 4];
        __syncthreads();
        const float* w = Wsp + ch * 256;
        float acc = bsp[ch];
        #pragma unroll 8
        for (int k = 0; k < 256; k += 4)
            acc += sh[half][k]*w[k] + sh[half][k+1]*w[k+1] + sh[half][k+2]*w[k+2] + sh[half][k+3]*w[k+3];
        p_i[row * 64 + ch] = acc;
    } else {
        const int pair = (blk - 1590) * 128 + tid;
        const int bi = pair >> 9, j = pair & (NN - 1);
        const int rj = (bi & ~(NN - 1)) + j;
        float ax = t[bi*3+0] - t[rj*3+0];
        float ay = t[bi*3+1] - t[rj*3+1];
        float az = t[bi*3+2] - t[rj*3+2];
        int bD = find_bin(sqrtf(ax*ax + ay*ay + az*az));
        float sx = sct[bi*3+0] - sct[rj*3+0];
        float sy = sct[bi*3+1] - sct[rj*3+1];
        float sz = sct[bi*3+2] - sct[rj*3+2];
        int bS = find_bin(sqrtf(sx*sx + sy*sy + sz*sz));
        binT[pair] = (unsigned short)(bD | (bS << 5));
    }
}

// ---- qL/qR (bf16): per-node contributions through W1 cols [0:64)/[64:128) ----
__global__ __launch_bounds__(128) void k_ql(const float* __restrict__ p_i,
        const float* __restrict__ W1,
        unsigned short* __restrict__ qLb, unsigned short* __restrict__ qRb)
{
    __shared__ float pr[64];
    const int row = blockIdx.x, tid = threadIdx.x;
    if (tid < 16) *(float4*)&pr[tid * 4] = *(const float4*)&p_i[row * 64 + tid * 4];
    __syncthreads();
    const float* w = W1 + tid * 236;
    float aL = 0.f, aR = 0.f;
    #pragma unroll
    for (int k = 0; k < 64; ++k) { aL += pr[k] * w[k]; aR += pr[k] * w[64 + k]; }
    qLb[row * 128 + tid] = f2bf(aL);
    qRb[row * 128 + tid] = f2bf(aR);
}

// LDS layout (bytes):
#define H1_OFF  0        // 64 rows x 256B bf16, XOR-swizzled
#define H2_OFF  16384    // 64 rows x 256B bf16, XOR-swizzled
#define WD_OFF  32768    // 23 rows x 272B (256 payload + 16 pad)
#define WSC_OFF 39024
#define LNP_OFF 45280    // 64 rows x 80B (8 float2 partials, padded stride 20 f)
#define SMEM_SZ 50400

// ---- main fused kernel: channel-split. 512 thr = 8 waves; wave w owns
//      channel-tile ct=w for both GEMMs, weights held in registers.
//      h1/h2 shared per block in LDS; LN via cross-wave partials. ----
__global__ __launch_bounds__(512, 4) void k_main(
    const float* __restrict__ pmask,
    const unsigned short* __restrict__ qLb, const unsigned short* __restrict__ qRb,
    const unsigned short* __restrict__ relTb, const unsigned short* __restrict__ WdTb,
    const unsigned short* __restrict__ WscTb, const unsigned short* __restrict__ binT,
    const unsigned short* __restrict__ w2a, const unsigned short* __restrict__ w3a,
    const float* __restrict__ b2, const float* __restrict__ b3,
    const float* __restrict__ lng, const float* __restrict__ lnb,
    float* __restrict__ out)
{
    __shared__ __align__(16) char smem[SMEM_SZ];

    const int tid  = threadIdx.x;
    const int l    = tid & 63;
    const int w    = tid >> 6;       // wave = channel tile ct
    const int jloc = l & 15;
    const int gq   = l >> 4;

    const int blk   = blockIdx.x;
    const int bi    = blk >> 3;              // b*512 + i
    const int i     = bi & (NN - 1);
    const int bbase = bi & ~(NN - 1);
    const int j0    = (blk & 7) * 64;        // block covers 64 rows

    // ---- per-wave weight fragments (registers), biases, LN params, masks ----
    bf16x8 w2r[4], w3r[4];
    #pragma unroll
    for (int ks = 0; ks < 4; ++ks) {
        w2r[ks] = *(const bf16x8*)(w2a + (w * 256 + ks * 64 + l) * 8);
        w3r[ks] = *(const bf16x8*)(w3a + (w * 256 + ks * 64 + l) * 8);
    }
    const int cch = w * 16 + gq * 4;
    const float4 b2f = *(const float4*)(b2 + cch);
    const float4 b3f = *(const float4*)(b3 + cch);
    const float4 g4  = *(const float4*)(lng + cch);
    const float4 be4 = *(const float4*)(lnb + cch);
    float maskv[4];
    #pragma unroll
    for (int tt = 0; tt < 4; ++tt)
        maskv[tt] = pmask[(size_t)bi * NN + j0 + tt * 16 + jloc];

    // ---- stage Wd/Wsc tables into LDS (padded stride 272B) ----
    #pragma unroll
    for (int it = 0; it < 2; ++it) {
        int idx = it * 512 + tid;
        if (idx < 736) {
            int tb = idx >= 368;
            int k = idx - (tb ? 368 : 0);
            int row = k >> 4, off = k & 15;
            const unsigned short* src = (tb ? WscTb : WdTb) + row * 128 + off * 8;
            *(uint4*)(smem + (tb ? WSC_OFF : WD_OFF) + row * 272 + off * 16) =
                *(const uint4*)src;
        }
    }
    __syncthreads();   // bar0: tables staged

    // ---- build h1 = relu(qL+qR+relT+Wd[bin]+Wsc[bin]) into LDS (bf16) ----
    {
        const int r = tid >> 3, q = tid & 7;        // row 0..63, ch-octet 0..7
        const unsigned bv = binT[bi * NN + j0 + r];
        const int bD = bv & 31, bS = (int)(bv >> 5);
        const unsigned short* qLp = qLb + (size_t)bi * 128;
        const unsigned short* qRp = qRb + (size_t)(bbase + j0 + r) * 128;
        const unsigned short* rTp = relTb + (size_t)(i - (j0 + r) + NN - 1) * 128;
        const int hswz = (r & 7) << 4;
        #pragma unroll
        for (int u = 0; u < 2; ++u) {
            const int c0 = q * 16 + u * 8;
            uint4 A = *(const uint4*)(qLp + c0);
            uint4 B = *(const uint4*)(qRp + c0);
            uint4 C = *(const uint4*)(rTp + c0);
            uint4 D = *(const uint4*)(smem + WD_OFF + bD * 272 + c0 * 2);
            uint4 E = *(const uint4*)(smem + WSC_OFF + bS * 272 + c0 * 2);
            uint4 P;
            P.x = pk2(A.x, B.x, C.x, D.x, E.x);
            P.y = pk2(A.y, B.y, C.y, D.y, E.y);
            P.z = pk2(A.z, B.z, C.z, D.z, E.z);
            P.w = pk2(A.w, B.w, C.w, D.w, E.w);
            *(uint4*)(smem + H1_OFF + ((r * 256 + c0 * 2) ^ hswz)) = P;
        }
    }
    __syncthreads();   // bar1: h1 complete

    const int rswz = (jloc & 7) << 4;

    // ---- GEMM2: wave computes its 16 channels for all 64 rows; h2 -> LDS ----
    #pragma unroll
    for (int tt = 0; tt < 4; ++tt) {
        const int rowb = (tt * 16 + jloc) * 256;
        f32x4 a2 = {0.f, 0.f, 0.f, 0.f};
        #pragma unroll
        for (int ks = 0; ks < 4; ++ks) {
            bf16x8 bfr = *(bf16x8*)(smem + H1_OFF + ((rowb + ks * 64 + gq * 16) ^ rswz));
            a2 = __builtin_amdgcn_mfma_f32_16x16x32_bf16(w2r[ks], bfr, a2, 0, 0, 0);
        }
        float y0 = fmaxf(a2[0] + b2f.x, 0.0f);
        float y1 = fmaxf(a2[1] + b2f.y, 0.0f);
        float y2 = fmaxf(a2[2] + b2f.z, 0.0f);
        float y3 = fmaxf(a2[3] + b2f.w, 0.0f);
        uint2 pk;
        pk.x = (unsigned)f2bf(y0) | ((unsigned)f2bf(y1) << 16);
        pk.y = (unsigned)f2bf(y2) | ((unsigned)f2bf(y3) << 16);
        *(uint2*)(smem + H2_OFF + ((rowb + cch * 2) ^ rswz)) = pk;
    }
    __syncthreads();   // bar2: h2 complete

    // ---- GEMM3 + cross-wave LN partials ----
    f32x4 acc3[4];
    float* lnp = (float*)(smem + LNP_OFF);
    #pragma unroll
    for (int tt = 0; tt < 4; ++tt) {
        const int rowb = (tt * 16 + jloc) * 256;
        f32x4 a3 = {0.f, 0.f, 0.f, 0.f};
        #pragma unroll
        for (int ks = 0; ks < 4; ++ks) {
            bf16x8 bfr = *(bf16x8*)(smem + H2_OFF + ((rowb + ks * 64 + gq * 16) ^ rswz));
            a3 = __builtin_amdgcn_mfma_f32_16x16x32_bf16(w3r[ks], bfr, a3, 0, 0, 0);
        }
        a3[0] += b3f.x; a3[1] += b3f.y; a3[2] += b3f.z; a3[3] += b3f.w;
        acc3[tt] = a3;
        float s1 = a3[0] + a3[1] + a3[2] + a3[3];
        float s2 = a3[0]*a3[0] + a3[1]*a3[1] + a3[2]*a3[2] + a3[3]*a3[3];
        s1 += __shfl_xor(s1, 16); s2 += __shfl_xor(s2, 16);
        s1 += __shfl_xor(s1, 32); s2 += __shfl_xor(s2, 32);
        if (l < 16) {
            float2 p2 = make_float2(s1, s2);
            *(float2*)(lnp + (tt * 16 + jloc) * 20 + w * 2) = p2;
        }
    }
    __syncthreads();   // bar3: LN partials complete

    // ---- finish LN, scale, mask, store ----
    #pragma unroll
    for (int tt = 0; tt < 4; ++tt) {
        const int row = tt * 16 + jloc;
        float s1 = 0.f, s2 = 0.f;
        #pragma unroll
        for (int pp = 0; pp < 4; ++pp) {
            float4 v = *(float4*)(lnp + row * 20 + pp * 4);
            s1 += v.x + v.z; s2 += v.y + v.w;
        }
        const float mean = s1 * (1.0f / 128.0f);
        const float var  = s2 * (1.0f / 128.0f) - mean * mean;
        const float rstd = rsqrtf(var + 1e-5f);
        const float mk = maskv[tt];
        f32x4 a3 = acc3[tt];
        float4 o;
        o.x = ((a3[0] - mean) * rstd * g4.x + be4.x) * mk;
        o.y = ((a3[1] - mean) * rstd * g4.y + be4.y) * mk;
        o.z = ((a3[2] - mean) * rstd * g4.z + be4.z) * mk;
        o.w = ((a3[3] - mean) * rstd * g4.w + be4.w) * mk;
        *(float4*)(out + ((size_t)(bi * NN + j0 + row)) * 128 + cch) = o;
    }
}

extern "C" void kernel_launch(void* const* d_in, const int* in_sizes, int n_in,
                              void* d_out, int out_size, void* d_ws, size_t ws_size,
                              hipStream_t stream)
{
    const float* s   = (const float*)d_in[0];
    const float* t   = (const float*)d_in[1];
    const float* sct = (const float*)d_in[2];
    const float* pm  = (const float*)d_in[3];
    const float* Wsp = (const float*)d_in[4];
    const float* bsp = (const float*)d_in[5];
    const float* Wrp = (const float*)d_in[6];
    const float* brp = (const float*)d_in[7];
    const float* W1  = (const float*)d_in[8];
    const float* b1  = (const float*)d_in[9];
    const float* W2  = (const float*)d_in[10];
    const float* b2  = (const float*)d_in[11];
    const float* W3  = (const float*)d_in[12];
    const float* b3  = (const float*)d_in[13];
    const float* lng = (const float*)d_in[14];
    const float* lnb = (const float*)d_in[15];

    float* ws = (float*)d_ws;
    float*          p_i   = ws;                                   // 65536 f
    unsigned short* qLb   = (unsigned short*)(ws + 65536);        // 131072 u16
    unsigned short* qRb   = (unsigned short*)(ws + 131072);       // 131072 u16
    unsigned short* relTb = (unsigned short*)(ws + 196608);       // 130944 u16
    unsigned short* WdTb  = (unsigned short*)(ws + 262144);       // 2944 u16
    unsigned short* WscTb = (unsigned short*)(ws + 263616);       // 2944 u16
    unsigned short* w2a   = (unsigned short*)(ws + 265088);       // 16384 u16
    unsigned short* w3a   = (unsigned short*)(ws + 273280);       // 16384 u16
    unsigned short* binT  = (unsigned short*)(ws + 281472);       // 524288 u16

    k_prep<<<5686, 128, 0, stream>>>(s, t, sct, Wsp, bsp, Wrp, brp, W1, b1, W2, W3,
                                     p_i, relTb, WdTb, WscTb, w2a, w3a, binT);
    k_ql<<<1024, 128, 0, stream>>>(p_i, W1, qLb, qRb);
    k_main<<<8192, 512, 0, stream>>>(pm, qLb, qRb, relTb, WdTb, WscTb, binT,
                                     w2a, w3a, b2, b3, lng, lnb, (float*)d_out);
}

// Round 8
// 128.424 us; speedup vs baseline: 1.7913x; 1.1486x over previous
//
#include <hip/hip_runtime.h>

#define NN 512

typedef __attribute__((ext_vector_type(8))) short bf16x8;
typedef __attribute__((ext_vector_type(4))) float f32x4;

__device__ __forceinline__ unsigned short f2bf(float x) {
    union { float f; unsigned u; } c; c.f = x;
    unsigned u = c.u + 0x7fffu + ((c.u >> 16) & 1u);
    return (unsigned short)(u >> 16);
}

__device__ __forceinline__ float blo(unsigned u) {
    union { unsigned x; float f; } c; c.x = u << 16; return c.f;
}
__device__ __forceinline__ float bhi(unsigned u) {
    union { unsigned x; float f; } c; c.x = u & 0xffff0000u; return c.f;
}

// sum 5 packed bf16-pairs in fp32, relu, repack
__device__ __forceinline__ unsigned pk2(unsigned a, unsigned b, unsigned c,
                                        unsigned d, unsigned e) {
    float lo = blo(a) + blo(b) + blo(c) + blo(d) + blo(e);
    float hi = bhi(a) + bhi(b) + bhi(c) + bhi(d) + bhi(e);
    lo = fmaxf(lo, 0.0f);
    hi = fmaxf(hi, 0.0f);
    return (unsigned)f2bf(lo) | ((unsigned)f2bf(hi) << 16);
}

__device__ __forceinline__ int find_bin(float d) {
    int bin = 22;  // 22 = "no bin" (zero row in WdTb/WscTb)
    #pragma unroll
    for (int k = 0; k < 22; ++k) {
        float lo = (float)(1e-3 + k * ((20.0 - 1e-3) / 21.0));
        float hi = (k < 21) ? (float)(1e-3 + (k + 1) * ((20.0 - 1e-3) / 21.0)) : 1e8f;
        if (d > lo && d < hi) bin = k;
    }
    return bin;
}

// ---- fused prep: bf16 W1-column gathers, W2/W3 MFMA-fragment packs,
//      bf16 relpos table, p_i node embed, per-pair distogram bin table ----
__global__ __launch_bounds__(128) void k_prep(
        const float* __restrict__ s, const float* __restrict__ t,
        const float* __restrict__ sct,
        const float* __restrict__ Wsp, const float* __restrict__ bsp,
        const float* __restrict__ Wrp, const float* __restrict__ brp,
        const float* __restrict__ W1, const float* __restrict__ b1,
        const float* __restrict__ W2, const float* __restrict__ W3,
        float* __restrict__ p_i, unsigned short* __restrict__ relTb,
        unsigned short* __restrict__ WdTb, unsigned short* __restrict__ WscTb,
        unsigned short* __restrict__ w2a, unsigned short* __restrict__ w3a,
        unsigned short* __restrict__ binT)
{
    __shared__ float sh[2][256];
    const int blk = blockIdx.x, tid = threadIdx.x;

    if (blk < 23) {
        const int bin = blk, c = tid;
        WdTb[bin * 128 + c]  = (bin < 22) ? f2bf(W1[c * 236 + 192 + bin]) : (unsigned short)0;
        WscTb[bin * 128 + c] = (bin < 22) ? f2bf(W1[c * 236 + 214 + bin]) : (unsigned short)0;
    } else if (blk < 55) {
        // pack W2/W3 into A-fragment order: entry idx = ct*256 + ks*64 + lane
        // holds W[ct*16 + (lane&15)][ks*32 + (lane>>4)*8 + e]
        const int seg = blk - 23;
        const int isW3 = seg >> 4;
        const int idx = (seg & 15) * 128 + tid;
        const int lane = idx & 63, ks = (idx >> 6) & 3, ct = idx >> 8;
        const float* W = isW3 ? W3 : W2;
        unsigned short* dst = isW3 ? w3a : w2a;
        const float* wp = W + (ct * 16 + (lane & 15)) * 128 + ks * 32 + (lane >> 4) * 8;
        unsigned r0 = (unsigned)f2bf(wp[0]) | ((unsigned)f2bf(wp[1]) << 16);
        unsigned r1 = (unsigned)f2bf(wp[2]) | ((unsigned)f2bf(wp[3]) << 16);
        unsigned r2 = (unsigned)f2bf(wp[4]) | ((unsigned)f2bf(wp[5]) << 16);
        unsigned r3 = (unsigned)f2bf(wp[6]) | ((unsigned)f2bf(wp[7]) << 16);
        uint4 v = { r0, r1, r2, r3 };
        *(uint4*)(dst + idx * 8) = v;
    } else if (blk < 1078) {
        // relTb[d] = bf16( (pos_emb(d) @ W_rp^T + b_rp) @ W1[:,128:192]^T + b1 )
        const int row = blk - 55;
        const float d = (float)(row - 511);
        if (tid < 32) {
            float f = powf(2056.0f, (float)tid * (1.0f / 32.0f));
            float ang = d * 3.14159265358979323846f / f;
            sh[0][tid] = sinf(ang);
            sh[0][tid + 32] = cosf(ang);
        }
        __syncthreads();
        if (tid < 64) {
            const float* wr = Wrp + tid * 64;
            float a = brp[tid];
            #pragma unroll
            for (int k = 0; k < 64; ++k) a += sh[0][k] * wr[k];
            sh[1][tid] = a;
        }
        __syncthreads();
        const float* w = W1 + tid * 236 + 128;
        float a = b1[tid];
        #pragma unroll
        for (int k = 0; k < 64; ++k) a += sh[1][k] * w[k];
        relTb[row * 128 + tid] = f2bf(a);
    } else if (blk < 1590) {
        // p_i = s @ Wsp^T + bsp, two rows per block
        const int half = tid >> 6, ch = tid & 63;
        const int row = (blk - 1078) * 2 + half;
        *(float4*)&sh[half][ch * 4] = *(const float4*)&s[row * 256 + ch * 4];
        __syncthreads();
        const float* w = Wsp + ch * 256;
        float acc = bsp[ch];
        #pragma unroll 8
        for (int k = 0; k < 256; k += 4)
            acc += sh[half][k]*w[k] + sh[half][k+1]*w[k+1] + sh[half][k+2]*w[k+2] + sh[half][k+3]*w[k+3];
        p_i[row * 64 + ch] = acc;
    } else {
        const int pair = (blk - 1590) * 128 + tid;
        const int bi = pair >> 9, j = pair & (NN - 1);
        const int rj = (bi & ~(NN - 1)) + j;
        float ax = t[bi*3+0] - t[rj*3+0];
        float ay = t[bi*3+1] - t[rj*3+1];
        float az = t[bi*3+2] - t[rj*3+2];
        int bD = find_bin(sqrtf(ax*ax + ay*ay + az*az));
        float sx = sct[bi*3+0] - sct[rj*3+0];
        float sy = sct[bi*3+1] - sct[rj*3+1];
        float sz = sct[bi*3+2] - sct[rj*3+2];
        int bS = find_bin(sqrtf(sx*sx + sy*sy + sz*sz));
        binT[pair] = (unsigned short)(bD | (bS << 5));
    }
}

// ---- qL/qR (bf16): per-node contributions through W1 cols [0:64)/[64:128) ----
__global__ __launch_bounds__(128) void k_ql(const float* __restrict__ p_i,
        const float* __restrict__ W1,
        unsigned short* __restrict__ qLb, unsigned short* __restrict__ qRb)
{
    __shared__ float pr[64];
    const int row = blockIdx.x, tid = threadIdx.x;
    if (tid < 16) *(float4*)&pr[tid * 4] = *(const float4*)&p_i[row * 64 + tid * 4];
    __syncthreads();
    const float* w = W1 + tid * 236;
    float aL = 0.f, aR = 0.f;
    #pragma unroll
    for (int k = 0; k < 64; ++k) { aL += pr[k] * w[k]; aR += pr[k] * w[64 + k]; }
    qLb[row * 128 + tid] = f2bf(aL);
    qRb[row * 128 + tid] = f2bf(aR);
}

// LDS layout (bytes):
#define H1_OFF  0        // 64 rows x 256B bf16, XOR-swizzled; reused as out-stage
#define H2_OFF  16384    // 64 rows x 256B bf16, XOR-swizzled; reused as out-stage
#define LNP_OFF 32768    // 64 rows x 80B (float2 partials, padded stride 20 f)
#define SMEM_SZ 37888

// ---- main fused kernel: channel-split. 512 thr = 8 waves; wave w owns
//      channel-tile ct=w for both GEMMs, weights held in registers.
//      h1/h2 shared per block in LDS; LN via cross-wave partials;
//      output bounced through LDS for full-line coalesced stores. ----
__global__ __launch_bounds__(512, 4) void k_main(
    const float* __restrict__ pmask,
    const unsigned short* __restrict__ qLb, const unsigned short* __restrict__ qRb,
    const unsigned short* __restrict__ relTb, const unsigned short* __restrict__ WdTb,
    const unsigned short* __restrict__ WscTb, const unsigned short* __restrict__ binT,
    const unsigned short* __restrict__ w2a, const unsigned short* __restrict__ w3a,
    const float* __restrict__ b2, const float* __restrict__ b3,
    const float* __restrict__ lng, const float* __restrict__ lnb,
    float* __restrict__ out)
{
    __shared__ __align__(16) char smem[SMEM_SZ];

    const int tid  = threadIdx.x;
    const int l    = tid & 63;
    const int w    = tid >> 6;       // wave = channel tile ct
    const int jloc = l & 15;
    const int gq   = l >> 4;

    const int blk   = blockIdx.x;
    const int bi    = blk >> 3;              // b*512 + i
    const int i     = bi & (NN - 1);
    const int bbase = bi & ~(NN - 1);
    const int j0    = (blk & 7) * 64;        // block covers 64 rows

    // ---- per-wave weight fragments (registers), biases, LN params, masks ----
    bf16x8 w2r[4], w3r[4];
    #pragma unroll
    for (int ks = 0; ks < 4; ++ks) {
        w2r[ks] = *(const bf16x8*)(w2a + (w * 256 + ks * 64 + l) * 8);
        w3r[ks] = *(const bf16x8*)(w3a + (w * 256 + ks * 64 + l) * 8);
    }
    const int cch = w * 16 + gq * 4;
    const float4 b2f = *(const float4*)(b2 + cch);
    const float4 b3f = *(const float4*)(b3 + cch);
    const float4 g4  = *(const float4*)(lng + cch);
    const float4 be4 = *(const float4*)(lnb + cch);
    float maskv[4];
    #pragma unroll
    for (int tt = 0; tt < 4; ++tt)
        maskv[tt] = pmask[(size_t)bi * NN + j0 + tt * 16 + jloc];

    // ---- build h1 = relu(qL+qR+relT+Wd[bin]+Wsc[bin]) into LDS (bf16) ----
    {
        const int r = tid >> 3, q = tid & 7;        // row 0..63, ch-octet 0..7
        const unsigned bv = binT[bi * NN + j0 + r];
        const int bD = bv & 31, bS = (int)(bv >> 5);
        const unsigned short* qLp = qLb + (size_t)bi * 128;
        const unsigned short* qRp = qRb + (size_t)(bbase + j0 + r) * 128;
        const unsigned short* rTp = relTb + (size_t)(i - (j0 + r) + NN - 1) * 128;
        const unsigned short* dTp = WdTb + bD * 128;
        const unsigned short* sTp = WscTb + bS * 128;
        const int hswz = (r & 7) << 4;
        #pragma unroll
        for (int u = 0; u < 2; ++u) {
            const int c0 = q * 16 + u * 8;
            uint4 A = *(const uint4*)(qLp + c0);
            uint4 B = *(const uint4*)(qRp + c0);
            uint4 C = *(const uint4*)(rTp + c0);
            uint4 D = *(const uint4*)(dTp + c0);
            uint4 E = *(const uint4*)(sTp + c0);
            uint4 P;
            P.x = pk2(A.x, B.x, C.x, D.x, E.x);
            P.y = pk2(A.y, B.y, C.y, D.y, E.y);
            P.z = pk2(A.z, B.z, C.z, D.z, E.z);
            P.w = pk2(A.w, B.w, C.w, D.w, E.w);
            *(uint4*)(smem + H1_OFF + ((r * 256 + c0 * 2) ^ hswz)) = P;
        }
    }
    __syncthreads();   // bar1: h1 complete

    const int rswz = (jloc & 7) << 4;

    // ---- GEMM2: wave computes its 16 channels for all 64 rows; h2 -> LDS ----
    #pragma unroll
    for (int tt = 0; tt < 4; ++tt) {
        const int rowb = (tt * 16 + jloc) * 256;
        f32x4 a2 = {0.f, 0.f, 0.f, 0.f};
        #pragma unroll
        for (int ks = 0; ks < 4; ++ks) {
            bf16x8 bfr = *(bf16x8*)(smem + H1_OFF + ((rowb + ks * 64 + gq * 16) ^ rswz));
            a2 = __builtin_amdgcn_mfma_f32_16x16x32_bf16(w2r[ks], bfr, a2, 0, 0, 0);
        }
        float y0 = fmaxf(a2[0] + b2f.x, 0.0f);
        float y1 = fmaxf(a2[1] + b2f.y, 0.0f);
        float y2 = fmaxf(a2[2] + b2f.z, 0.0f);
        float y3 = fmaxf(a2[3] + b2f.w, 0.0f);
        uint2 pk;
        pk.x = (unsigned)f2bf(y0) | ((unsigned)f2bf(y1) << 16);
        pk.y = (unsigned)f2bf(y2) | ((unsigned)f2bf(y3) << 16);
        *(uint2*)(smem + H2_OFF + ((rowb + cch * 2) ^ rswz)) = pk;
    }
    __syncthreads();   // bar2: h2 complete

    // ---- GEMM3 + cross-wave LN partials ----
    f32x4 acc3[4];
    float* lnp = (float*)(smem + LNP_OFF);
    #pragma unroll
    for (int tt = 0; tt < 4; ++tt) {
        const int rowb = (tt * 16 + jloc) * 256;
        f32x4 a3 = {0.f, 0.f, 0.f, 0.f};
        #pragma unroll
        for (int ks = 0; ks < 4; ++ks) {
            bf16x8 bfr = *(bf16x8*)(smem + H2_OFF + ((rowb + ks * 64 + gq * 16) ^ rswz));
            a3 = __builtin_amdgcn_mfma_f32_16x16x32_bf16(w3r[ks], bfr, a3, 0, 0, 0);
        }
        a3[0] += b3f.x; a3[1] += b3f.y; a3[2] += b3f.z; a3[3] += b3f.w;
        acc3[tt] = a3;
        float s1 = a3[0] + a3[1] + a3[2] + a3[3];
        float s2 = a3[0]*a3[0] + a3[1]*a3[1] + a3[2]*a3[2] + a3[3]*a3[3];
        s1 += __shfl_xor(s1, 16); s2 += __shfl_xor(s2, 16);
        s1 += __shfl_xor(s1, 32); s2 += __shfl_xor(s2, 32);
        if (l < 16) {
            float2 p2 = make_float2(s1, s2);
            *(float2*)(lnp + (tt * 16 + jloc) * 20 + w * 2) = p2;
        }
    }
    __syncthreads();   // bar3: LN partials done; h1/h2 reads all drained

    // ---- finish LN, scale, mask, write to out-stage (swizzled slots) ----
    #pragma unroll
    for (int tt = 0; tt < 4; ++tt) {
        const int row = tt * 16 + jloc;
        float s1 = 0.f, s2 = 0.f;
        #pragma unroll
        for (int pp = 0; pp < 4; ++pp) {
            float4 v = *(float4*)(lnp + row * 20 + pp * 4);
            s1 += v.x + v.z; s2 += v.y + v.w;
        }
        const float mean = s1 * (1.0f / 128.0f);
        const float var  = s2 * (1.0f / 128.0f) - mean * mean;
        const float rstd = rsqrtf(var + 1e-5f);
        const float mk = maskv[tt];
        f32x4 a3 = acc3[tt];
        f32x4 o;
        o[0] = ((a3[0] - mean) * rstd * g4.x + be4.x) * mk;
        o[1] = ((a3[1] - mean) * rstd * g4.y + be4.y) * mk;
        o[2] = ((a3[2] - mean) * rstd * g4.z + be4.z) * mk;
        o[3] = ((a3[3] - mean) * rstd * g4.w + be4.w) * mk;
        const int slot = (w * 4 + gq) ^ (row & 31);
        *(f32x4*)(smem + row * 512 + slot * 16) = o;
    }
    __syncthreads();   // bar4: out-stage complete

    // ---- block-wide coalesced copy: 4 x 8KB, each wave stores 1KB/line ----
    float* ob = out + ((size_t)(bi * NN + j0)) * 128;
    #pragma unroll
    for (int it = 0; it < 4; ++it) {
        const int boff = it * 8192 + tid * 16;      // linear byte offset
        const int row  = boff >> 9;
        const int slot = (boff >> 4) & 31;
        const int sslt = slot ^ (row & 31);
        f32x4 v = *(f32x4*)(smem + row * 512 + sslt * 16);
        __builtin_nontemporal_store(v, (f32x4*)(ob + (boff >> 2)));
    }
}

extern "C" void kernel_launch(void* const* d_in, const int* in_sizes, int n_in,
                              void* d_out, int out_size, void* d_ws, size_t ws_size,
                              hipStream_t stream)
{
    const float* s   = (const float*)d_in[0];
    const float* t   = (const float*)d_in[1];
    const float* sct = (const float*)d_in[2];
    const float* pm  = (const float*)d_in[3];
    const float* Wsp = (const float*)d_in[4];
    const float* bsp = (const float*)d_in[5];
    const float* Wrp = (const float*)d_in[6];
    const float* brp = (const float*)d_in[7];
    const float* W1  = (const float*)d_in[8];
    const float* b1  = (const float*)d_in[9];
    const float* W2  = (const float*)d_in[10];
    const float* b2  = (const float*)d_in[11];
    const float* W3  = (const float*)d_in[12];
    const float* b3  = (const float*)d_in[13];
    const float* lng = (const float*)d_in[14];
    const float* lnb = (const float*)d_in[15];

    float* ws = (float*)d_ws;
    float*          p_i   = ws;                                   // 65536 f
    unsigned short* qLb   = (unsigned short*)(ws + 65536);        // 131072 u16
    unsigned short* qRb   = (unsigned short*)(ws + 131072);       // 131072 u16
    unsigned short* relTb = (unsigned short*)(ws + 196608);       // 130944 u16
    unsigned short* WdTb  = (unsigned short*)(ws + 262144);       // 2944 u16
    unsigned short* WscTb = (unsigned short*)(ws + 263616);       // 2944 u16
    unsigned short* w2a   = (unsigned short*)(ws + 265088);       // 16384 u16
    unsigned short* w3a   = (unsigned short*)(ws + 273280);       // 16384 u16
    unsigned short* binT  = (unsigned short*)(ws + 281472);       // 524288 u16

    k_prep<<<5686, 128, 0, stream>>>(s, t, sct, Wsp, bsp, Wrp, brp, W1, b1, W2, W3,
                                     p_i, relTb, WdTb, WscTb, w2a, w3a, binT);
    k_ql<<<1024, 128, 0, stream>>>(p_i, W1, qLb, qRb);
    k_main<<<8192, 512, 0, stream>>>(pm, qLb, qRb, relTb, WdTb, WscTb, binT,
                                     w2a, w3a, b2, b3, lng, lnb, (float*)d_out);
}